// Round 2
// baseline (179829.309 us; speedup 1.0000x reference)
//
#include <hip/hip_runtime.h>
#include <hip/hip_fp16.h>
#include <math.h>

#define HN 1024
#define FN 256
#define LN 4096
#define NBLK 256
#define NTHR 512
#define NSLOT (LN - 1)   // 4095 sequential steps

// ws layout (floats):
//   pg1[2][4096]  : partial gates1, [unit][gate] layout, double buffer
//   h2b[2][1024]  : h2 double buffer
//   barrier       : 2048 u32 at WS_BAR
#define WS_PG1 0
#define WS_H2B 8192
#define WS_BAR 10240
// bar (u32 idx): grp_arrive g at g*32 ; root at 520 ; grp_release g at 1024+g*32 ; abort at 1536

typedef unsigned long long u64;

__device__ __forceinline__ float sigm(float x) { return 1.0f / (1.0f + __expf(-x)); }
__device__ __forceinline__ float tanh_f(float x) {
    x = fminf(fmaxf(x, -15.0f), 15.0f);
    float e = __expf(2.0f * x);
    return (e - 1.0f) / (e + 1.0f);
}
__device__ __forceinline__ float aload(const float* p) {
    return __hip_atomic_load(p, __ATOMIC_RELAXED, __HIP_MEMORY_SCOPE_AGENT);
}
__device__ __forceinline__ u64 aload64(const u64* p) {
    return __hip_atomic_load(p, __ATOMIC_RELAXED, __HIP_MEMORY_SCOPE_AGENT);
}
__device__ __forceinline__ void astore(float* p, float v) {
    __hip_atomic_store(p, v, __ATOMIC_RELAXED, __HIP_MEMORY_SCOPE_AGENT);
}
__device__ __forceinline__ float2 u2f2(unsigned long long v) {
    union { u64 u; float2 f; } c; c.u = v; return c.f;
}
__device__ __forceinline__ __half2 u2h2(unsigned v) {
    union { unsigned u; __half2 h; } c; c.u = v; return c.h;
}
// 8-term fp16 dot via packed v_pk_fma_f16, f32 master accumulate
__device__ __forceinline__ float dot8(uint4 w, uint4 x, float acc) {
    __half2 s = __hmul2(u2h2(w.x), u2h2(x.x));
    s = __hfma2(u2h2(w.y), u2h2(x.y), s);
    s = __hfma2(u2h2(w.z), u2h2(x.z), s);
    s = __hfma2(u2h2(w.w), u2h2(x.w), s);
    return acc + __low2float(s) + __high2float(s);
}

__global__ void ws_init(unsigned* bar) {
    int t = blockIdx.x * blockDim.x + threadIdx.x;
    for (int i = t; i < 2048; i += 256) bar[i] = 0u;
}

// Tree barrier: 16 groups x 16 blocks arrivals, fan-out release to 16 lines.
// <=16 pollers per cacheline. Epoch-monotonic release values (no reset hazard).
__device__ __forceinline__ bool gridbar(unsigned* bar, unsigned epoch, unsigned* s_ok) {
    __syncthreads();   // drains this block's vmcnt -> our sc1 stores are done
    if (threadIdx.x == 0) {
        const int g = (int)(blockIdx.x >> 4);
        unsigned* arr = bar + g * 32;
        unsigned* root = bar + 520;
        unsigned* rel = bar + 1024 + g * 32;
        unsigned* abo = bar + 1536;
        unsigned ok = 1u;
        unsigned a = __hip_atomic_fetch_add(arr, 1u, __ATOMIC_ACQ_REL, __HIP_MEMORY_SCOPE_AGENT);
        if (a == 15u) {
            __hip_atomic_store(arr, 0u, __ATOMIC_RELAXED, __HIP_MEMORY_SCOPE_AGENT);
            unsigned r = __hip_atomic_fetch_add(root, 1u, __ATOMIC_ACQ_REL, __HIP_MEMORY_SCOPE_AGENT);
            if (r == 15u) {
                __hip_atomic_store(root, 0u, __ATOMIC_RELAXED, __HIP_MEMORY_SCOPE_AGENT);
                #pragma unroll
                for (int i = 0; i < 16; ++i)
                    __hip_atomic_store(bar + 1024 + i * 32, epoch, __ATOMIC_RELEASE, __HIP_MEMORY_SCOPE_AGENT);
            }
        }
        unsigned it = 0;
        while (__hip_atomic_load(rel, __ATOMIC_ACQUIRE, __HIP_MEMORY_SCOPE_AGENT) < epoch) {
            __builtin_amdgcn_s_sleep(2);
            if (((++it) & 127u) == 0u) {
                if (__hip_atomic_load(abo, __ATOMIC_RELAXED, __HIP_MEMORY_SCOPE_AGENT) != 0u) { ok = 0u; break; }
                if (it > (1u << 18)) {
                    __hip_atomic_store(abo, 1u, __ATOMIC_RELAXED, __HIP_MEMORY_SCOPE_AGENT);
                    ok = 0u; break;
                }
            }
        }
        *s_ok = ok;
    }
    __syncthreads();
    return *s_ok != 0u;
}

__global__ __launch_bounds__(NTHR)
void lstm_main(const float* __restrict__ feat, const float* __restrict__ tgt,
               const float* __restrict__ Wih1, const float* __restrict__ bih1,
               const float* __restrict__ Whh1, const float* __restrict__ bhh1,
               const float* __restrict__ Wih2, const float* __restrict__ bih2,
               const float* __restrict__ Whh2, const float* __restrict__ bhh2,
               const float* __restrict__ Wout, const float* __restrict__ bout,
               float* __restrict__ out, float* __restrict__ ws)
{
    // block b owns units [4b,4b+4) of layer1 (16 gate rows) and layer2.
    // local row lr = g*4 + ui  (g = gate 0..3 i,f,g,o ; ui = unit 0..3)
    __shared__ __align__(16) __half w1f[16 * FN];    //  8 KB  W_ih1[:, :256]
    __shared__ __align__(16) __half w1h[16 * HN];    // 32 KB  W_hh1
    __shared__ __align__(16) __half w2i[16 * HN];    // 32 KB  W_ih2
    __shared__ __align__(16) __half w2h[16 * HN];    // 32 KB  W_hh2
    __shared__ __align__(16) __half wc4[4 * HN];     //  8 KB  W_ih1[:,256], [unit][gate]
    __shared__ __align__(16) float  wout_s[HN];      //  4 KB
    __shared__ __align__(16) __half h1h[HN];         //  2 KB
    __shared__ __align__(16) __half h2h[HN];         //  2 KB
    __shared__ __align__(16) __half fh[FN];          //  0.5 KB
    __shared__ float b1s[16], b2s[16], g2s[16];
    __shared__ float rsum[NTHR / 64];
    __shared__ float bouts;
    __shared__ unsigned s_ok;

    const int tid = threadIdx.x;
    const int b4  = (int)blockIdx.x * 4;
    float* pg1buf = ws + WS_PG1;
    float* h2buf  = ws + WS_H2B;
    unsigned* bar = (unsigned*)(ws + WS_BAR);
    const u64* pg1q = (const u64*)pg1buf;

    // ---------------- prologue: stage weights (fp16) ----------------
    for (int e = tid; e < 16 * FN; e += NTHR) {
        int lr = e >> 8, c = e & (FN - 1);
        int gr = (lr >> 2) * HN + b4 + (lr & 3);
        w1f[lr * FN + c] = __float2half(Wih1[gr * (FN + 1) + c]);
    }
    for (int e = tid; e < 16 * HN; e += NTHR) {
        int lr = e >> 10, c = e & (HN - 1);
        int gr = (lr >> 2) * HN + b4 + (lr & 3);
        w1h[lr * HN + c] = __float2half(Whh1[gr * HN + c]);
        w2i[lr * HN + c] = __float2half(Wih2[gr * HN + c]);
        w2h[lr * HN + c] = __float2half(Whh2[gr * HN + c]);
    }
    for (int e = tid; e < 4 * HN; e += NTHR) {
        int u = e >> 2, g = e & 3;
        wc4[e] = __float2half(Wih1[(g * HN + u) * (FN + 1) + FN]);
    }
    for (int e = tid; e < HN; e += NTHR) wout_s[e] = Wout[e];
    if (tid < 16) {
        int gr = (tid >> 2) * HN + b4 + (tid & 3);
        b1s[tid] = bih1[gr] + bhh1[gr];
        b2s[tid] = bih2[gr] + bhh2[gr];
    }
    if (tid == 0) bouts = bout[0];
    if (tid < FN) fh[tid] = __float2half(feat[tid]);
    if (tid < 4) astore(&h2buf[HN + b4 + tid], 0.f);   // h2_{-1} = 0 (buffer 1)
    __syncthreads();

    // priming: PG1(0) = W_ih1[:, :256] @ f_0 + biases   (h1_{-1} = 0)
    {
        const int lr = tid >> 5, sub = tid & 31;
        uint4 wf = *reinterpret_cast<const uint4*>(&w1f[lr * FN + sub * 8]);
        uint4 fc = *reinterpret_cast<const uint4*>(&fh[sub * 8]);
        float acc = dot8(wf, fc, 0.f);
        #pragma unroll
        for (int m = 1; m <= 16; m <<= 1) acc += __shfl_xor(acc, m);
        if (sub == 0)
            astore(&pg1buf[(b4 + (lr & 3)) * 4 + (lr >> 2)], acc + b1s[lr]);
    }

    float c1a = 0.f, c1b = 0.f;   // replicated c1 (units tid, tid+512)
    float c2v = 0.f;              // c2 for unit b4+tid (tid<4)
    float p = tgt[0];
    float lacc = 0.f;
    unsigned ep = 1;

    if (!gridbar(bar, ep, &s_ok)) return;

    for (int s = 0; s < NSLOT; ++s) {
        const int par = s & 1;
        const int u0 = tid, u1 = tid + NTHR;

        // ---- phase A: load h2(t-1)/PG1(t), stage f(t+1), pred(t-1) ----
        float h2v0 = aload(&h2buf[(par ^ 1) * HN + u0]);
        float h2v1 = aload(&h2buf[(par ^ 1) * HN + u1]);
        u64 pgA0 = aload64(&pg1q[par * 2048 + u0 * 2]);
        u64 pgA1 = aload64(&pg1q[par * 2048 + u0 * 2 + 1]);
        u64 pgB0 = aload64(&pg1q[par * 2048 + u1 * 2]);
        u64 pgB1 = aload64(&pg1q[par * 2048 + u1 * 2 + 1]);
        if (tid < FN) fh[tid] = __float2half(feat[(s + 1) * FN + tid]);
        h2h[u0] = __float2half(h2v0);
        h2h[u1] = __float2half(h2v1);
        float pp = wout_s[u0] * h2v0 + wout_s[u1] * h2v1;
        #pragma unroll
        for (int m = 1; m <= 32; m <<= 1) pp += __shfl_xor(pp, m);
        if ((tid & 63) == 0) rsum[tid >> 6] = pp;
        __syncthreads();
        float dred = rsum[0] + rsum[1] + rsum[2] + rsum[3]
                   + rsum[4] + rsum[5] + rsum[6] + rsum[7];
        if (s > 0) {
            p = dred + bouts + p;
            float d = p - tgt[s];
            lacc += d * d;
        }

        // ---- phase B: reconstruct full h1(t) (replicated, deterministic) ----
        {
            float2 ab = u2f2(pgA0), cd = u2f2(pgA1);   // (i,f), (g,o) pre-acts
            uint2 wu = *reinterpret_cast<const uint2*>(&wc4[u0 * 4]);
            float2 w01 = __half22float2(u2h2(wu.x));
            float2 w23 = __half22float2(u2h2(wu.y));
            float gi = ab.x + p * w01.x, gf = ab.y + p * w01.y;
            float gg = cd.x + p * w23.x, go = cd.y + p * w23.y;
            c1a = sigm(gf) * c1a + sigm(gi) * tanh_f(gg);
            h1h[u0] = __float2half(sigm(go) * tanh_f(c1a));
            ab = u2f2(pgB0); cd = u2f2(pgB1);
            wu = *reinterpret_cast<const uint2*>(&wc4[u1 * 4]);
            w01 = __half22float2(u2h2(wu.x));
            w23 = __half22float2(u2h2(wu.y));
            gi = ab.x + p * w01.x; gf = ab.y + p * w01.y;
            gg = cd.x + p * w23.x; go = cd.y + p * w23.y;
            c1b = sigm(gf) * c1b + sigm(gi) * tanh_f(gg);
            h1h[u1] = __float2half(sigm(go) * tanh_f(c1b));
        }
        __syncthreads();

        // ---- phase C: mv1 -> PG1(t+1), mv2 -> gates2(t). b128 LDS, conflict-free ----
        {
            const int lr = tid >> 5, sub = tid & 31;
            uint4 h1c[4];
            #pragma unroll
            for (int j = 0; j < 4; ++j)
                h1c[j] = *reinterpret_cast<const uint4*>(&h1h[sub * 8 + j * 256]);
            // mv1
            float acc;
            {
                uint4 wf = *reinterpret_cast<const uint4*>(&w1f[lr * FN + sub * 8]);
                uint4 fc = *reinterpret_cast<const uint4*>(&fh[sub * 8]);
                acc = dot8(wf, fc, 0.f);
                #pragma unroll
                for (int j = 0; j < 4; ++j) {
                    uint4 ww = *reinterpret_cast<const uint4*>(&w1h[lr * HN + sub * 8 + j * 256]);
                    acc = dot8(ww, h1c[j], acc);
                }
            }
            #pragma unroll
            for (int m = 1; m <= 16; m <<= 1) acc += __shfl_xor(acc, m);
            if (sub == 0)
                astore(&pg1buf[(par ^ 1) * 4096 + (b4 + (lr & 3)) * 4 + (lr >> 2)],
                       acc + b1s[lr]);
            // mv2
            float a2 = 0.f;
            #pragma unroll
            for (int j = 0; j < 4; ++j) {
                uint4 wi = *reinterpret_cast<const uint4*>(&w2i[lr * HN + sub * 8 + j * 256]);
                a2 = dot8(wi, h1c[j], a2);
                uint4 wh = *reinterpret_cast<const uint4*>(&w2h[lr * HN + sub * 8 + j * 256]);
                uint4 hc = *reinterpret_cast<const uint4*>(&h2h[sub * 8 + j * 256]);
                a2 = dot8(wh, hc, a2);
            }
            #pragma unroll
            for (int m = 1; m <= 16; m <<= 1) a2 += __shfl_xor(a2, m);
            if (sub == 0) g2s[lr] = a2 + b2s[lr];
        }
        __syncthreads();
        if (tid < 4) {
            float gi = sigm(g2s[tid]);
            float gf = sigm(g2s[4 + tid]);
            float gg = tanh_f(g2s[8 + tid]);
            float go = sigm(g2s[12 + tid]);
            c2v = gf * c2v + gi * gg;
            astore(&h2buf[par * HN + b4 + tid], go * tanh_f(c2v));
        }
        ++ep;
        if (!gridbar(bar, ep, &s_ok)) return;
    }

    // ---- epilogue: final pred + loss ----
    {
        const int par = NSLOT & 1;  // 1
        const int u0 = tid, u1 = tid + NTHR;
        float h2v0 = aload(&h2buf[(par ^ 1) * HN + u0]);
        float h2v1 = aload(&h2buf[(par ^ 1) * HN + u1]);
        float pp = wout_s[u0] * h2v0 + wout_s[u1] * h2v1;
        #pragma unroll
        for (int m = 1; m <= 32; m <<= 1) pp += __shfl_xor(pp, m);
        if ((tid & 63) == 0) rsum[tid >> 6] = pp;
        __syncthreads();
        float dred = rsum[0] + rsum[1] + rsum[2] + rsum[3]
                   + rsum[4] + rsum[5] + rsum[6] + rsum[7];
        p = dred + bouts + p;
        float d = p - tgt[LN - 1];
        lacc += d * d;
        if (blockIdx.x == 0 && tid == 0) out[0] = sqrtf(lacc / (float)LN);
    }
}

extern "C" void kernel_launch(void* const* d_in, const int* in_sizes, int n_in,
                              void* d_out, int out_size, void* d_ws, size_t ws_size,
                              hipStream_t stream) {
    (void)in_sizes; (void)n_in; (void)out_size; (void)ws_size;
    const float* feat = (const float*)d_in[0];
    const float* tgt  = (const float*)d_in[1];
    const float* Wih1 = (const float*)d_in[2];
    const float* bih1 = (const float*)d_in[3];
    const float* Whh1 = (const float*)d_in[4];
    const float* bhh1 = (const float*)d_in[5];
    const float* Wih2 = (const float*)d_in[6];
    const float* bih2 = (const float*)d_in[7];
    const float* Whh2 = (const float*)d_in[8];
    const float* bhh2 = (const float*)d_in[9];
    const float* Wout = (const float*)d_in[10];
    const float* bout = (const float*)d_in[11];
    float* out = (float*)d_out;
    float* ws  = (float*)d_ws;

    unsigned* bar = (unsigned*)(ws + WS_BAR);
    hipLaunchKernelGGL(ws_init, dim3(8), dim3(256), 0, stream, bar);

    const float *a0 = feat, *a1 = tgt, *a2 = Wih1, *a3 = bih1, *a4 = Whh1, *a5 = bhh1,
                *a6 = Wih2, *a7 = bih2, *a8 = Whh2, *a9 = bhh2, *a10 = Wout, *a11 = bout;
    float *a12 = out, *a13 = ws;
    void* args[] = { &a0, &a1, &a2, &a3, &a4, &a5, &a6, &a7, &a8, &a9, &a10, &a11, &a12, &a13 };
    hipError_t e = hipLaunchCooperativeKernel((void*)lstm_main, dim3(NBLK), dim3(NTHR),
                                              args, 0, stream);
    if (e != hipSuccess) {
        hipLaunchKernelGGL(lstm_main, dim3(NBLK), dim3(NTHR), 0, stream,
                           feat, tgt, Wih1, bih1, Whh1, bhh1, Wih2, bih2, Whh2, bhh2,
                           Wout, bout, out, ws);
    }
}

// Round 3
// 35739.807 us; speedup vs baseline: 5.0316x; 5.0316x over previous
//
#include <hip/hip_runtime.h>
#include <hip/hip_fp16.h>
#include <math.h>

#define HN 1024
#define FN 256
#define LN 4096
#define NBLK 256
#define NTHR 512
#define NSLOT (LN - 1)   // 4095 sequential steps

// ws layout (float indices):
//   pg1[2][4096]  : partial gates1, [unit][gate] layout, double buffer
//   h2b[2][1024]  : h2 double buffer
//   tags[256]     : per-block epoch tags (u32) at WS_TAG
//   abort flag    : u32 at WS_ABO
#define WS_PG1 0
#define WS_H2B 8192
#define WS_TAG 10240
#define WS_ABO 10500

typedef unsigned long long u64;

__device__ __forceinline__ float sigm(float x) { return 1.0f / (1.0f + __expf(-x)); }
__device__ __forceinline__ float tanh_f(float x) {
    x = fminf(fmaxf(x, -15.0f), 15.0f);
    float e = __expf(2.0f * x);
    return (e - 1.0f) / (e + 1.0f);
}
__device__ __forceinline__ float aload(const float* p) {
    return __hip_atomic_load(p, __ATOMIC_RELAXED, __HIP_MEMORY_SCOPE_AGENT);
}
__device__ __forceinline__ u64 aload64(const u64* p) {
    return __hip_atomic_load(p, __ATOMIC_RELAXED, __HIP_MEMORY_SCOPE_AGENT);
}
__device__ __forceinline__ void astore(float* p, float v) {
    __hip_atomic_store(p, v, __ATOMIC_RELAXED, __HIP_MEMORY_SCOPE_AGENT);
}
__device__ __forceinline__ float2 u2f2(u64 v) {
    union { u64 u; float2 f; } c; c.u = v; return c.f;
}
__device__ __forceinline__ __half2 u2h2(unsigned v) {
    union { unsigned u; __half2 h; } c; c.u = v; return c.h;
}
// 8-term fp16 dot via packed v_pk_fma_f16, f32 master accumulate
__device__ __forceinline__ float dot8(uint4 w, uint4 x, float acc) {
    __half2 s = __hmul2(u2h2(w.x), u2h2(x.x));
    s = __hfma2(u2h2(w.y), u2h2(x.y), s);
    s = __hfma2(u2h2(w.z), u2h2(x.z), s);
    s = __hfma2(u2h2(w.w), u2h2(x.w), s);
    return acc + __low2float(s) + __high2float(s);
}

__global__ void ws_init(float* ws) {
    int t = threadIdx.x;
    if (t <= 260) ((unsigned*)ws)[WS_TAG + t] = 0u;  // tags[256] + abort
}

// Poller: wave 7 spins (RELAXED, no cache ops) on all 256 tags until >= need.
// On timeout/abort: sets/observes abort flag, s_ok=0 -> whole grid bails out.
#define POLLWAIT(need_)                                                        \
    if ((tid >> 6) == 7) {                                                     \
        const int L = tid & 63;                                                \
        const unsigned need = (unsigned)(need_);                               \
        unsigned ok = 1u, it = 0;                                              \
        for (;;) {                                                             \
            unsigned t0 = __hip_atomic_load(&tagw[L      ], __ATOMIC_RELAXED, __HIP_MEMORY_SCOPE_AGENT); \
            unsigned t1 = __hip_atomic_load(&tagw[L +  64], __ATOMIC_RELAXED, __HIP_MEMORY_SCOPE_AGENT); \
            unsigned t2 = __hip_atomic_load(&tagw[L + 128], __ATOMIC_RELAXED, __HIP_MEMORY_SCOPE_AGENT); \
            unsigned t3 = __hip_atomic_load(&tagw[L + 192], __ATOMIC_RELAXED, __HIP_MEMORY_SCOPE_AGENT); \
            int rdy = (t0 >= need) && (t1 >= need) && (t2 >= need) && (t3 >= need); \
            if (__all(rdy)) break;                                             \
            __builtin_amdgcn_s_sleep(1);                                       \
            if (((++it) & 255u) == 0u) {                                       \
                if (__hip_atomic_load(abop, __ATOMIC_RELAXED, __HIP_MEMORY_SCOPE_AGENT) != 0u) { ok = 0u; break; } \
                if (it > (1u << 16)) {                                         \
                    __hip_atomic_store(abop, 1u, __ATOMIC_RELAXED, __HIP_MEMORY_SCOPE_AGENT); \
                    ok = 0u; break;                                            \
                }                                                              \
            }                                                                  \
        }                                                                      \
        if (L == 0) s_ok = ok;                                                 \
    }                                                                          \
    __syncthreads();                                                           \
    if (s_ok == 0u) return;

__global__ __launch_bounds__(NTHR)
void lstm_main(const float* __restrict__ feat, const float* __restrict__ tgt,
               const float* __restrict__ Wih1, const float* __restrict__ bih1,
               const float* __restrict__ Whh1, const float* __restrict__ bhh1,
               const float* __restrict__ Wih2, const float* __restrict__ bih2,
               const float* __restrict__ Whh2, const float* __restrict__ bhh2,
               const float* __restrict__ Wout, const float* __restrict__ bout,
               float* __restrict__ out, float* __restrict__ ws)
{
    // block b owns units [4b,4b+4) of layer1 (16 gate rows) and layer2.
    // local row lr = g*4 + ui  (g = gate 0..3 i,f,g,o ; ui = unit 0..3)
    __shared__ __align__(16) __half w1f[16 * FN];    //  8 KB  W_ih1[:, :256]
    __shared__ __align__(16) __half w1h[16 * HN];    // 32 KB  W_hh1
    __shared__ __align__(16) __half w2i[16 * HN];    // 32 KB  W_ih2
    __shared__ __align__(16) __half w2h[16 * HN];    // 32 KB  W_hh2
    __shared__ __align__(16) __half wc4[4 * HN];     //  8 KB  W_ih1[:,256], [unit][gate]
    __shared__ __align__(16) float  wout_s[HN];      //  4 KB
    __shared__ __align__(16) __half h1h[HN];         //  2 KB
    __shared__ __align__(16) __half h2h[HN];         //  2 KB
    __shared__ __align__(16) __half fh[FN];          //  0.5 KB
    __shared__ float b1s[16], b2s[16], g2s[16];
    __shared__ float rsum[NTHR / 64];
    __shared__ float bouts;
    __shared__ unsigned s_ok;

    const int tid = threadIdx.x;
    const int b4  = (int)blockIdx.x * 4;
    float* pg1buf = ws + WS_PG1;
    float* h2buf  = ws + WS_H2B;
    unsigned* tagw = (unsigned*)(ws + WS_TAG);
    unsigned* abop = (unsigned*)(ws + WS_ABO);
    const u64* pg1q = (const u64*)pg1buf;

    // ---------------- prologue: stage weights (fp16) ----------------
    for (int e = tid; e < 16 * FN; e += NTHR) {
        int lr = e >> 8, c = e & (FN - 1);
        int gr = (lr >> 2) * HN + b4 + (lr & 3);
        w1f[lr * FN + c] = __float2half(Wih1[gr * (FN + 1) + c]);
    }
    for (int e = tid; e < 16 * HN; e += NTHR) {
        int lr = e >> 10, c = e & (HN - 1);
        int gr = (lr >> 2) * HN + b4 + (lr & 3);
        w1h[lr * HN + c] = __float2half(Whh1[gr * HN + c]);
        w2i[lr * HN + c] = __float2half(Wih2[gr * HN + c]);
        w2h[lr * HN + c] = __float2half(Whh2[gr * HN + c]);
    }
    for (int e = tid; e < 4 * HN; e += NTHR) {
        int u = e >> 2, g = e & 3;
        wc4[e] = __float2half(Wih1[(g * HN + u) * (FN + 1) + FN]);
    }
    for (int e = tid; e < HN; e += NTHR) wout_s[e] = Wout[e];
    if (tid < 16) {
        int gr = (tid >> 2) * HN + b4 + (tid & 3);
        b1s[tid] = bih1[gr] + bhh1[gr];
        b2s[tid] = bih2[gr] + bhh2[gr];
    }
    if (tid == 0) bouts = bout[0];
    if (tid < FN) fh[tid] = __float2half(feat[tid]);
    if (tid < 4) astore(&h2buf[HN + b4 + tid], 0.f);   // h2_{-1} = 0 (buffer 1)
    __syncthreads();

    // priming: PG1(0) = W_ih1[:, :256] @ f_0 + biases   (h1_{-1} = 0)
    {
        const int lr = tid >> 5, sub = tid & 31;
        uint4 wf = *reinterpret_cast<const uint4*>(&w1f[lr * FN + sub * 8]);
        uint4 fc = *reinterpret_cast<const uint4*>(&fh[sub * 8]);
        float acc = dot8(wf, fc, 0.f);
        #pragma unroll
        for (int m = 1; m <= 16; m <<= 1) acc += __shfl_xor(acc, m);
        if (sub == 0)
            astore(&pg1buf[(b4 + (lr & 3)) * 4 + (lr >> 2)], acc + b1s[lr]);
    }
    __syncthreads();   // drains all waves' pg1/h2 stores (vmcnt(0) before barrier)
    if (tid == 0)      // publish {pg1(0), h2(-1)} : tag = 1 (RELEASE = one drain)
        __hip_atomic_store(&tagw[blockIdx.x], 1u, __ATOMIC_RELEASE, __HIP_MEMORY_SCOPE_AGENT);

    float c1a = 0.f, c1b = 0.f;   // replicated c1 (units tid, tid+512)
    float c2r[4] = {0.f, 0.f, 0.f, 0.f};   // c2 for units b4..b4+3 (tid0 only uses)
    float p = tgt[0];
    float lacc = 0.f;

    for (int s = 0; s < NSLOT; ++s) {
        const int par = s & 1;
        const int u0 = tid, u1 = tid + NTHR;

        // ---- dataflow wait: all blocks published {pg1(s), h2(s-1)} ----
        POLLWAIT(s + 1);

        // ---- phase A: load h2(s-1)/PG1(s), stage f(s+1), pred(s-1) ----
        float h2v0 = aload(&h2buf[(par ^ 1) * HN + u0]);
        float h2v1 = aload(&h2buf[(par ^ 1) * HN + u1]);
        u64 pgA0 = aload64(&pg1q[par * 2048 + u0 * 2]);
        u64 pgA1 = aload64(&pg1q[par * 2048 + u0 * 2 + 1]);
        u64 pgB0 = aload64(&pg1q[par * 2048 + u1 * 2]);
        u64 pgB1 = aload64(&pg1q[par * 2048 + u1 * 2 + 1]);
        if (tid < FN) fh[tid] = __float2half(feat[(s + 1) * FN + tid]);
        h2h[u0] = __float2half(h2v0);
        h2h[u1] = __float2half(h2v1);
        float pp = wout_s[u0] * h2v0 + wout_s[u1] * h2v1;
        #pragma unroll
        for (int m = 1; m <= 32; m <<= 1) pp += __shfl_xor(pp, m);
        if ((tid & 63) == 0) rsum[tid >> 6] = pp;
        __syncthreads();
        float dred = rsum[0] + rsum[1] + rsum[2] + rsum[3]
                   + rsum[4] + rsum[5] + rsum[6] + rsum[7];
        if (s > 0) {
            p = dred + bouts + p;
            float d = p - tgt[s];
            lacc += d * d;
        }

        // ---- phase B: reconstruct full h1(s) (replicated, deterministic) ----
        {
            float2 ab = u2f2(pgA0), cd = u2f2(pgA1);   // (i,f), (g,o) pre-acts
            uint2 wu = *reinterpret_cast<const uint2*>(&wc4[u0 * 4]);
            float2 w01 = __half22float2(u2h2(wu.x));
            float2 w23 = __half22float2(u2h2(wu.y));
            float gi = ab.x + p * w01.x, gf = ab.y + p * w01.y;
            float gg = cd.x + p * w23.x, go = cd.y + p * w23.y;
            c1a = sigm(gf) * c1a + sigm(gi) * tanh_f(gg);
            h1h[u0] = __float2half(sigm(go) * tanh_f(c1a));
            ab = u2f2(pgB0); cd = u2f2(pgB1);
            wu = *reinterpret_cast<const uint2*>(&wc4[u1 * 4]);
            w01 = __half22float2(u2h2(wu.x));
            w23 = __half22float2(u2h2(wu.y));
            gi = ab.x + p * w01.x; gf = ab.y + p * w01.y;
            gg = cd.x + p * w23.x; go = cd.y + p * w23.y;
            c1b = sigm(gf) * c1b + sigm(gi) * tanh_f(gg);
            h1h[u1] = __float2half(sigm(go) * tanh_f(c1b));
        }
        __syncthreads();

        // ---- phase C: mv1 -> PG1(s+1), mv2 -> gates2(s). b128 LDS, conflict-free ----
        {
            const int lr = tid >> 5, sub = tid & 31;
            uint4 h1c[4];
            #pragma unroll
            for (int j = 0; j < 4; ++j)
                h1c[j] = *reinterpret_cast<const uint4*>(&h1h[sub * 8 + j * 256]);
            float acc;
            {
                uint4 wf = *reinterpret_cast<const uint4*>(&w1f[lr * FN + sub * 8]);
                uint4 fc = *reinterpret_cast<const uint4*>(&fh[sub * 8]);
                acc = dot8(wf, fc, 0.f);
                #pragma unroll
                for (int j = 0; j < 4; ++j) {
                    uint4 ww = *reinterpret_cast<const uint4*>(&w1h[lr * HN + sub * 8 + j * 256]);
                    acc = dot8(ww, h1c[j], acc);
                }
            }
            #pragma unroll
            for (int m = 1; m <= 16; m <<= 1) acc += __shfl_xor(acc, m);
            if (sub == 0)
                astore(&pg1buf[(par ^ 1) * 4096 + (b4 + (lr & 3)) * 4 + (lr >> 2)],
                       acc + b1s[lr]);
            float a2 = 0.f;
            #pragma unroll
            for (int j = 0; j < 4; ++j) {
                uint4 wi = *reinterpret_cast<const uint4*>(&w2i[lr * HN + sub * 8 + j * 256]);
                a2 = dot8(wi, h1c[j], a2);
                uint4 wh = *reinterpret_cast<const uint4*>(&w2h[lr * HN + sub * 8 + j * 256]);
                uint4 hc = *reinterpret_cast<const uint4*>(&h2h[sub * 8 + j * 256]);
                a2 = dot8(wh, hc, a2);
            }
            #pragma unroll
            for (int m = 1; m <= 16; m <<= 1) a2 += __shfl_xor(a2, m);
            if (sub == 0) g2s[lr] = a2 + b2s[lr];
        }
        __syncthreads();   // g2s visible; also drains all waves' pg1 stores

        // ---- publish: tid0 computes this block's 4 layer-2 cells, stores h2(s),
        //      then one RELEASE tag store (single vmcnt drain orders h2+pg1). ----
        if (tid == 0) {
            #pragma unroll
            for (int u = 0; u < 4; ++u) {
                float gi = sigm(g2s[u]);
                float gf = sigm(g2s[4 + u]);
                float gg = tanh_f(g2s[8 + u]);
                float go = sigm(g2s[12 + u]);
                c2r[u] = gf * c2r[u] + gi * gg;
                astore(&h2buf[par * HN + b4 + u], go * tanh_f(c2r[u]));
            }
            __hip_atomic_store(&tagw[blockIdx.x], (unsigned)(s + 2),
                               __ATOMIC_RELEASE, __HIP_MEMORY_SCOPE_AGENT);
        }
    }

    // ---- epilogue: wait for h2(NSLOT-1), final pred + loss ----
    POLLWAIT(NSLOT + 1);
    {
        const int par = NSLOT & 1;  // 1
        const int u0 = tid, u1 = tid + NTHR;
        float h2v0 = aload(&h2buf[(par ^ 1) * HN + u0]);
        float h2v1 = aload(&h2buf[(par ^ 1) * HN + u1]);
        float pp = wout_s[u0] * h2v0 + wout_s[u1] * h2v1;
        #pragma unroll
        for (int m = 1; m <= 32; m <<= 1) pp += __shfl_xor(pp, m);
        if ((tid & 63) == 0) rsum[tid >> 6] = pp;
        __syncthreads();
        float dred = rsum[0] + rsum[1] + rsum[2] + rsum[3]
                   + rsum[4] + rsum[5] + rsum[6] + rsum[7];
        p = dred + bouts + p;
        float d = p - tgt[LN - 1];
        lacc += d * d;
        if (blockIdx.x == 0 && tid == 0) out[0] = sqrtf(lacc / (float)LN);
    }
}

extern "C" void kernel_launch(void* const* d_in, const int* in_sizes, int n_in,
                              void* d_out, int out_size, void* d_ws, size_t ws_size,
                              hipStream_t stream) {
    (void)in_sizes; (void)n_in; (void)out_size; (void)ws_size;
    const float* feat = (const float*)d_in[0];
    const float* tgt  = (const float*)d_in[1];
    const float* Wih1 = (const float*)d_in[2];
    const float* bih1 = (const float*)d_in[3];
    const float* Whh1 = (const float*)d_in[4];
    const float* bhh1 = (const float*)d_in[5];
    const float* Wih2 = (const float*)d_in[6];
    const float* bih2 = (const float*)d_in[7];
    const float* Whh2 = (const float*)d_in[8];
    const float* bhh2 = (const float*)d_in[9];
    const float* Wout = (const float*)d_in[10];
    const float* bout = (const float*)d_in[11];
    float* out = (float*)d_out;
    float* ws  = (float*)d_ws;

    hipLaunchKernelGGL(ws_init, dim3(1), dim3(512), 0, stream, ws);

    const float *a0 = feat, *a1 = tgt, *a2 = Wih1, *a3 = bih1, *a4 = Whh1, *a5 = bhh1,
                *a6 = Wih2, *a7 = bih2, *a8 = Whh2, *a9 = bhh2, *a10 = Wout, *a11 = bout;
    float *a12 = out, *a13 = ws;
    void* args[] = { &a0, &a1, &a2, &a3, &a4, &a5, &a6, &a7, &a8, &a9, &a10, &a11, &a12, &a13 };
    hipError_t e = hipLaunchCooperativeKernel((void*)lstm_main, dim3(NBLK), dim3(NTHR),
                                              args, 0, stream);
    if (e != hipSuccess) {
        hipLaunchKernelGGL(lstm_main, dim3(NBLK), dim3(NTHR), 0, stream,
                           feat, tgt, Wih1, bih1, Whh1, bhh1, Wih2, bih2, Whh2, bhh2,
                           Wout, bout, out, ws);
    }
}

// Round 4
// 19805.838 us; speedup vs baseline: 9.0796x; 1.8045x over previous
//
#include <hip/hip_runtime.h>
#include <hip/hip_fp16.h>
#include <math.h>

#define HN 1024
#define FN 256
#define LN 4096
#define NBLK 256
#define NTHR 512
#define NSLOT (LN - 1)   // 4095 sequential steps

// ws layout (float indices):
//   wq[2][1024][2] u64 self-tagged words at 0   (8192 floats)
//     wordA = i16 | f16<<16 | g16<<32 | ep16<<48     (pg1 pre-acts, step ep)
//     wordB = o16 | h2_16<<16 |    0 <<32 | ep16<<48 (o pre-act step ep, h2(ep-1))
//   abort u32 at float index 8192
#define WS_ABO 8192

typedef unsigned long long u64;

__device__ __forceinline__ float sigm(float x) { return 1.0f / (1.0f + __expf(-x)); }
__device__ __forceinline__ float tanh_f(float x) {
    x = fminf(fmaxf(x, -15.0f), 15.0f);
    float e = __expf(2.0f * x);
    return (e - 1.0f) / (e + 1.0f);
}
__device__ __forceinline__ u64 aload64(const u64* p) {
    return __hip_atomic_load(p, __ATOMIC_RELAXED, __HIP_MEMORY_SCOPE_AGENT);
}
__device__ __forceinline__ void astore64(u64* p, u64 v) {
    __hip_atomic_store(p, v, __ATOMIC_RELAXED, __HIP_MEMORY_SCOPE_AGENT);
}
__device__ __forceinline__ unsigned short f2hb(float x) {
    union { __half h; unsigned short u; } c; c.h = __float2half(x); return c.u;
}
__device__ __forceinline__ float hbf(u64 w, int sh) {   // fp16 bits at [sh,sh+16) -> f32
    union { unsigned short u; __half h; } c; c.u = (unsigned short)(w >> sh);
    return __half2float(c.h);
}
__device__ __forceinline__ __half2 u2h2(unsigned v) {
    union { unsigned u; __half2 h; } c; c.u = v; return c.h;
}
// 8-term fp16 dot via packed v_pk_fma_f16, f32 master accumulate
__device__ __forceinline__ float dot8(uint4 w, uint4 x, float acc) {
    __half2 s = __hmul2(u2h2(w.x), u2h2(x.x));
    s = __hfma2(u2h2(w.y), u2h2(x.y), s);
    s = __hfma2(u2h2(w.z), u2h2(x.z), s);
    s = __hfma2(u2h2(w.w), u2h2(x.w), s);
    return acc + __low2float(s) + __high2float(s);
}

__global__ void ws_init(float* ws) {
    if (threadIdx.x == 0) ((unsigned*)ws)[WS_ABO] = 0u;   // abort flag only
}

__global__ __launch_bounds__(NTHR)
void lstm_main(const float* __restrict__ feat, const float* __restrict__ tgt,
               const float* __restrict__ Wih1, const float* __restrict__ bih1,
               const float* __restrict__ Whh1, const float* __restrict__ bhh1,
               const float* __restrict__ Wih2, const float* __restrict__ bih2,
               const float* __restrict__ Whh2, const float* __restrict__ bhh2,
               const float* __restrict__ Wout, const float* __restrict__ bout,
               float* __restrict__ out, float* __restrict__ ws)
{
    // block b owns units [4b,4b+4) of layer1 (16 gate rows) and layer2.
    // local row lr = g*4 + ui  (g = gate 0..3 i,f,g,o ; ui = unit 0..3)
    __shared__ __align__(16) __half w1f[16 * FN];    //  8 KB  W_ih1[:, :256]
    __shared__ __align__(16) __half w1h[16 * HN];    // 32 KB  W_hh1
    __shared__ __align__(16) __half w2i[16 * HN];    // 32 KB  W_ih2
    __shared__ __align__(16) __half w2h[16 * HN];    // 32 KB  W_hh2
    __shared__ __align__(16) __half wc4[4 * HN];     //  8 KB  W_ih1[:,256], [unit][gate]
    __shared__ __align__(16) float  wout_s[HN];      //  4 KB
    __shared__ __align__(16) __half h1h[HN];         //  2 KB
    __shared__ __align__(16) __half h2h[HN];         //  2 KB
    __shared__ __align__(16) __half fh[FN];          //  0.5 KB
    __shared__ float b1s[16], b2s[16], g1s[16], g2s[16];
    __shared__ float rsum[NTHR / 64];
    __shared__ float bouts;
    __shared__ unsigned s_bad;

    const int tid = threadIdx.x;
    const int b4  = (int)blockIdx.x * 4;
    u64* wq = (u64*)ws;
    unsigned* abop = (unsigned*)ws + WS_ABO;

    // ---------------- prologue: stage weights (fp16) ----------------
    for (int e = tid; e < 16 * FN; e += NTHR) {
        int lr = e >> 8, c = e & (FN - 1);
        int gr = (lr >> 2) * HN + b4 + (lr & 3);
        w1f[lr * FN + c] = __float2half(Wih1[gr * (FN + 1) + c]);
    }
    for (int e = tid; e < 16 * HN; e += NTHR) {
        int lr = e >> 10, c = e & (HN - 1);
        int gr = (lr >> 2) * HN + b4 + (lr & 3);
        w1h[lr * HN + c] = __float2half(Whh1[gr * HN + c]);
        w2i[lr * HN + c] = __float2half(Wih2[gr * HN + c]);
        w2h[lr * HN + c] = __float2half(Whh2[gr * HN + c]);
    }
    for (int e = tid; e < 4 * HN; e += NTHR) {
        int u = e >> 2, g = e & 3;
        wc4[e] = __float2half(Wih1[(g * HN + u) * (FN + 1) + FN]);
    }
    for (int e = tid; e < HN; e += NTHR) wout_s[e] = Wout[e];
    if (tid < 16) {
        int gr = (tid >> 2) * HN + b4 + (tid & 3);
        b1s[tid] = bih1[gr] + bhh1[gr];
        b2s[tid] = bih2[gr] + bhh2[gr];
    }
    if (tid == 0) { bouts = bout[0]; s_bad = 0u; }
    if (tid < FN) fh[tid] = __float2half(feat[tid]);
    __syncthreads();

    // priming: pg1(0) pre-acts = W_ih1[:, :256] @ f_0 + biases   (h1_{-1} = 0)
    {
        const int lr = tid >> 5, sub = tid & 31;
        uint4 wf = *reinterpret_cast<const uint4*>(&w1f[lr * FN + sub * 8]);
        uint4 fc = *reinterpret_cast<const uint4*>(&fh[sub * 8]);
        float acc = dot8(wf, fc, 0.f);
        #pragma unroll
        for (int m = 1; m <= 16; m <<= 1) acc += __shfl_xor(acc, m);
        if (sub == 0) g1s[lr] = acc + b1s[lr];
    }
    __syncthreads();
    if (tid < 4) {   // publish {pg1(0), h2(-1)=0} with ep=0 into parity-0 buffer
        u64 A = (u64)f2hb(g1s[tid]) | ((u64)f2hb(g1s[4 + tid]) << 16)
              | ((u64)f2hb(g1s[8 + tid]) << 32);        // ep = 0
        u64 B = (u64)f2hb(g1s[12 + tid]);               // h2 = 0, ep = 0
        u64* qn = wq + (size_t)(b4 + tid) * 2;
        astore64(qn, A);
        astore64(qn + 1, B);
    }

    float c1a = 0.f, c1b = 0.f;     // replicated c1 (units tid, tid+512)
    float c2v = 0.f;                // c2 for unit b4+tid (tid<4)
    float p = tgt[0];
    float lacc = 0.f;

    for (int s = 0; s < NSLOT; ++s) {
        const int par = s & 1;
        const int u0 = tid, u1 = tid + NTHR;

        // ---- self-tagged poll: the poll IS the data load (no tags, no ordering) ----
        u64 wA0, wB0, wA1, wB1;
        {
            const u64* q = wq + (size_t)par * 2048;
            const unsigned need = (unsigned)s;
            unsigned it = 0;
            for (;;) {
                wA0 = aload64(&q[u0 * 2]);
                wB0 = aload64(&q[u0 * 2 + 1]);
                wA1 = aload64(&q[u1 * 2]);
                wB1 = aload64(&q[u1 * 2 + 1]);
                if ((unsigned)(wA0 >> 48) == need && (unsigned)(wB0 >> 48) == need &&
                    (unsigned)(wA1 >> 48) == need && (unsigned)(wB1 >> 48) == need) break;
                __builtin_amdgcn_s_sleep(6);
                if (((++it) & 255u) == 0u) {
                    if (__hip_atomic_load(abop, __ATOMIC_RELAXED, __HIP_MEMORY_SCOPE_AGENT) != 0u
                        || it > (1u << 14)) {
                        __hip_atomic_store(abop, 1u, __ATOMIC_RELAXED, __HIP_MEMORY_SCOPE_AGENT);
                        s_bad = 1u;
                        break;
                    }
                }
            }
        }

        // ---- phase A: h2 from wordB; stage f(s+1); pred(s-1) ----
        float h2v0 = hbf(wB0, 16);
        float h2v1 = hbf(wB1, 16);
        if (tid < FN) fh[tid] = __float2half(feat[(s + 1) * FN + tid]);
        h2h[u0] = __float2half(h2v0);
        h2h[u1] = __float2half(h2v1);
        float pp = wout_s[u0] * h2v0 + wout_s[u1] * h2v1;
        #pragma unroll
        for (int m = 1; m <= 32; m <<= 1) pp += __shfl_xor(pp, m);
        if ((tid & 63) == 0) rsum[tid >> 6] = pp;
        __syncthreads();
        if (s_bad != 0u) return;
        float dred = rsum[0] + rsum[1] + rsum[2] + rsum[3]
                   + rsum[4] + rsum[5] + rsum[6] + rsum[7];
        if (s > 0) {
            p = dred + bouts + p;
            float d = p - tgt[s];
            lacc += d * d;
        }

        // ---- phase B: h1(s) from gates + p (replicated, deterministic) ----
        {
            uint2 wu = *reinterpret_cast<const uint2*>(&wc4[u0 * 4]);
            float2 w01 = __half22float2(u2h2(wu.x));
            float2 w23 = __half22float2(u2h2(wu.y));
            float gi = hbf(wA0, 0)  + p * w01.x;
            float gf = hbf(wA0, 16) + p * w01.y;
            float gg = hbf(wA0, 32) + p * w23.x;
            float go = hbf(wB0, 0)  + p * w23.y;
            c1a = sigm(gf) * c1a + sigm(gi) * tanh_f(gg);
            h1h[u0] = __float2half(sigm(go) * tanh_f(c1a));
            wu = *reinterpret_cast<const uint2*>(&wc4[u1 * 4]);
            w01 = __half22float2(u2h2(wu.x));
            w23 = __half22float2(u2h2(wu.y));
            gi = hbf(wA1, 0)  + p * w01.x;
            gf = hbf(wA1, 16) + p * w01.y;
            gg = hbf(wA1, 32) + p * w23.x;
            go = hbf(wB1, 0)  + p * w23.y;
            c1b = sigm(gf) * c1b + sigm(gi) * tanh_f(gg);
            h1h[u1] = __float2half(sigm(go) * tanh_f(c1b));
        }
        __syncthreads();

        // ---- phase C: mv1 -> pg1(s+1) slice, mv2 -> gates2(s) slice ----
        {
            const int lr = tid >> 5, sub = tid & 31;
            uint4 h1c[4];
            #pragma unroll
            for (int j = 0; j < 4; ++j)
                h1c[j] = *reinterpret_cast<const uint4*>(&h1h[sub * 8 + j * 256]);
            float acc;
            {
                uint4 wf = *reinterpret_cast<const uint4*>(&w1f[lr * FN + sub * 8]);
                uint4 fc = *reinterpret_cast<const uint4*>(&fh[sub * 8]);
                acc = dot8(wf, fc, 0.f);
                #pragma unroll
                for (int j = 0; j < 4; ++j) {
                    uint4 ww = *reinterpret_cast<const uint4*>(&w1h[lr * HN + sub * 8 + j * 256]);
                    acc = dot8(ww, h1c[j], acc);
                }
            }
            #pragma unroll
            for (int m = 1; m <= 16; m <<= 1) acc += __shfl_xor(acc, m);
            if (sub == 0) g1s[lr] = acc + b1s[lr];
            float a2 = 0.f;
            #pragma unroll
            for (int j = 0; j < 4; ++j) {
                uint4 wi = *reinterpret_cast<const uint4*>(&w2i[lr * HN + sub * 8 + j * 256]);
                a2 = dot8(wi, h1c[j], a2);
                uint4 wh = *reinterpret_cast<const uint4*>(&w2h[lr * HN + sub * 8 + j * 256]);
                uint4 hc = *reinterpret_cast<const uint4*>(&h2h[sub * 8 + j * 256]);
                a2 = dot8(wh, hc, a2);
            }
            #pragma unroll
            for (int m = 1; m <= 16; m <<= 1) a2 += __shfl_xor(a2, m);
            if (sub == 0) g2s[lr] = a2 + b2s[lr];
        }
        __syncthreads();

        // ---- publish: tids 0..3 in parallel: layer-2 cell, pack, 2 atomic u64 stores ----
        if (tid < 4) {
            float gi2 = sigm(g2s[tid]);
            float gf2 = sigm(g2s[4 + tid]);
            float gg2 = tanh_f(g2s[8 + tid]);
            float go2 = sigm(g2s[12 + tid]);
            c2v = gf2 * c2v + gi2 * gg2;
            float h2n = go2 * tanh_f(c2v);
            const u64 ep = (u64)(unsigned)(s + 1) << 48;
            u64 A = (u64)f2hb(g1s[tid]) | ((u64)f2hb(g1s[4 + tid]) << 16)
                  | ((u64)f2hb(g1s[8 + tid]) << 32) | ep;
            u64 B = (u64)f2hb(g1s[12 + tid]) | ((u64)f2hb(h2n) << 16) | ep;
            u64* qn = wq + (size_t)((s + 1) & 1) * 2048 + (size_t)(b4 + tid) * 2;
            astore64(qn, A);
            astore64(qn + 1, B);
        }
    }

    // ---- epilogue: poll h2(NSLOT-1) (ep == NSLOT), final pred + loss ----
    {
        const int par = NSLOT & 1;  // 1
        const int u0 = tid, u1 = tid + NTHR;
        u64 wB0, wB1;
        {
            const u64* q = wq + (size_t)par * 2048;
            const unsigned need = (unsigned)NSLOT;
            unsigned it = 0;
            for (;;) {
                wB0 = aload64(&q[u0 * 2 + 1]);
                wB1 = aload64(&q[u1 * 2 + 1]);
                if ((unsigned)(wB0 >> 48) == need && (unsigned)(wB1 >> 48) == need) break;
                __builtin_amdgcn_s_sleep(6);
                if (((++it) & 255u) == 0u) {
                    if (__hip_atomic_load(abop, __ATOMIC_RELAXED, __HIP_MEMORY_SCOPE_AGENT) != 0u
                        || it > (1u << 14)) {
                        __hip_atomic_store(abop, 1u, __ATOMIC_RELAXED, __HIP_MEMORY_SCOPE_AGENT);
                        s_bad = 1u;
                        break;
                    }
                }
            }
        }
        float h2v0 = hbf(wB0, 16);
        float h2v1 = hbf(wB1, 16);
        float pp = wout_s[u0] * h2v0 + wout_s[u1] * h2v1;
        #pragma unroll
        for (int m = 1; m <= 32; m <<= 1) pp += __shfl_xor(pp, m);
        if ((tid & 63) == 0) rsum[tid >> 6] = pp;
        __syncthreads();
        if (s_bad != 0u) return;
        float dred = rsum[0] + rsum[1] + rsum[2] + rsum[3]
                   + rsum[4] + rsum[5] + rsum[6] + rsum[7];
        p = dred + bouts + p;
        float d = p - tgt[LN - 1];
        lacc += d * d;
        if (blockIdx.x == 0 && tid == 0) out[0] = sqrtf(lacc / (float)LN);
    }
}

extern "C" void kernel_launch(void* const* d_in, const int* in_sizes, int n_in,
                              void* d_out, int out_size, void* d_ws, size_t ws_size,
                              hipStream_t stream) {
    (void)in_sizes; (void)n_in; (void)out_size; (void)ws_size;
    const float* feat = (const float*)d_in[0];
    const float* tgt  = (const float*)d_in[1];
    const float* Wih1 = (const float*)d_in[2];
    const float* bih1 = (const float*)d_in[3];
    const float* Whh1 = (const float*)d_in[4];
    const float* bhh1 = (const float*)d_in[5];
    const float* Wih2 = (const float*)d_in[6];
    const float* bih2 = (const float*)d_in[7];
    const float* Whh2 = (const float*)d_in[8];
    const float* bhh2 = (const float*)d_in[9];
    const float* Wout = (const float*)d_in[10];
    const float* bout = (const float*)d_in[11];
    float* out = (float*)d_out;
    float* ws  = (float*)d_ws;

    hipLaunchKernelGGL(ws_init, dim3(1), dim3(64), 0, stream, ws);

    const float *a0 = feat, *a1 = tgt, *a2 = Wih1, *a3 = bih1, *a4 = Whh1, *a5 = bhh1,
                *a6 = Wih2, *a7 = bih2, *a8 = Whh2, *a9 = bhh2, *a10 = Wout, *a11 = bout;
    float *a12 = out, *a13 = ws;
    void* args[] = { &a0, &a1, &a2, &a3, &a4, &a5, &a6, &a7, &a8, &a9, &a10, &a11, &a12, &a13 };
    hipError_t e = hipLaunchCooperativeKernel((void*)lstm_main, dim3(NBLK), dim3(NTHR),
                                              args, 0, stream);
    if (e != hipSuccess) {
        hipLaunchKernelGGL(lstm_main, dim3(NBLK), dim3(NTHR), 0, stream,
                           feat, tgt, Wih1, bih1, Whh1, bhh1, Wih2, bih2, Whh2, bhh2,
                           Wout, bout, out, ws);
    }
}